// Round 1
// 104.043 us; speedup vs baseline: 1.7024x; 1.7024x over previous
//
#include <hip/hip_runtime.h>

#define B 4
#define N 4096
#define M 4096
#define C 32
#define BN (B * N)

typedef short bf16x8 __attribute__((ext_vector_type(8)));  // 8 bf16 in 4 VGPRs
typedef float f32x4  __attribute__((ext_vector_type(4)));
typedef unsigned int u32x4 __attribute__((ext_vector_type(4)));

__device__ __forceinline__ float bf16lo(unsigned int u) { return __uint_as_float(u << 16); }
__device__ __forceinline__ float bf16hi(unsigned int u) { return __uint_as_float(u & 0xffff0000u); }

// Exact 3-way truncation split of 8 f32 values into 3 bf16x8 planes.
// f32 mantissa = 24 bits; each plane captures >=8 bits and each residual
// subtraction is exact (same-exponent cancellation), so f = h + m + l EXACTLY.
__device__ __forceinline__ void split3(const float f[8], bf16x8& h, bf16x8& m, bf16x8& l) {
    u32x4 hw, mw, lw;
    #pragma unroll
    for (int p = 0; p < 4; ++p) {
        const float f0 = f[2*p], f1 = f[2*p+1];
        const unsigned int h0 = __float_as_uint(f0) & 0xffff0000u;
        const unsigned int h1 = __float_as_uint(f1) & 0xffff0000u;
        hw[p] = h1 | (h0 >> 16);
        const float r0 = f0 - __uint_as_float(h0);
        const float r1 = f1 - __uint_as_float(h1);
        const unsigned int m0 = __float_as_uint(r0) & 0xffff0000u;
        const unsigned int m1 = __float_as_uint(r1) & 0xffff0000u;
        mw[p] = m1 | (m0 >> 16);
        const float s0 = r0 - __uint_as_float(m0);
        const float s1 = r1 - __uint_as_float(m1);
        lw[p] = (__float_as_uint(s1) & 0xffff0000u) | (__float_as_uint(s0) >> 16);
    }
    h = __builtin_bit_cast(bf16x8, hw);
    m = __builtin_bit_cast(bf16x8, mw);
    l = __builtin_bit_cast(bf16x8, lw);
}

// Grid: 512 blocks, 256 threads.
// Both paths: bi -> ms = bi&7 (m-split of 512), nb = (bi>>3)&15 (256 n rows), b = bi>>7.
// Each wave: 64 n rows (4 MFMA tiles), scans 512 m via 32 MFMA m-tiles.
// Key = dot - y2/2 (argmax == argmin dist; x2 cancels). C-operand seeds -y2/2.
// f32 path: inputs split exactly into 3 bf16 planes (hi/mid/lo, 8 mantissa bits
// each = full 24-bit f32 mantissa); 9 MFMA terms reconstruct the f32 dot with
// only f32-accumulation rounding -> argmax-faithful vs the f32 reference.
__global__ __launch_bounds__(256, 2)
void nn_main(const void* __restrict__ xptr, const void* __restrict__ yptr,
             const unsigned short* __restrict__ tptr,
             float* __restrict__ wD, int* __restrict__ wI) {
    const bool is_bf16 = (tptr[0] == 0x4120);  // bf16(10.0)=0x4120; f32 low half = 0x0000

    __shared__ float y2s[512];          // -0.5*y2 for this m-split

    const int tid  = threadIdx.x;
    const int lane = tid & 63;
    const int bi   = blockIdx.x;

    const int wv   = tid >> 6;
    const int col  = lane & 15;
    const int quad = lane >> 4;
    const int ms   = bi & 7;
    const int nb   = (bi >> 3) & 15;
    const int b    = bi >> 7;
    const int n_base = nb * 256 + wv * 64;

    float bD[4][4];
    int   bI[4][4];
    #pragma unroll
    for (int t = 0; t < 4; ++t)
        #pragma unroll
        for (int r = 0; r < 4; ++r) { bD[t][r] = -__builtin_inff(); bI[t][r] = 0; }

    if (is_bf16) {
        const unsigned short* yp = (const unsigned short*)yptr;
        const unsigned short* xp = (const unsigned short*)xptr;

        // ---- stage -0.5*y2 for the 512 m rows of this split ----
        for (int r = tid; r < 512; r += 256) {
            const int m = ms * 512 + r;
            const uint4* p = (const uint4*)(yp + ((size_t)b * M + m) * C);
            float s = 0.f;
            #pragma unroll
            for (int i = 0; i < 4; ++i) {
                uint4 v = p[i];
                float f;
                f = bf16lo(v.x); s = fmaf(f, f, s); f = bf16hi(v.x); s = fmaf(f, f, s);
                f = bf16lo(v.y); s = fmaf(f, f, s); f = bf16hi(v.y); s = fmaf(f, f, s);
                f = bf16lo(v.z); s = fmaf(f, f, s); f = bf16hi(v.z); s = fmaf(f, f, s);
                f = bf16lo(v.w); s = fmaf(f, f, s); f = bf16hi(v.w); s = fmaf(f, f, s);
            }
            y2s[r] = -0.5f * s;
        }

        // ---- A fragments: lane holds X[n=base+t*16+col][quad*8 .. +7] ----
        bf16x8 af[4];
        #pragma unroll
        for (int t = 0; t < 4; ++t)
            af[t] = *(const bf16x8*)(xp + ((size_t)b * N + n_base + t * 16 + col) * C + quad * 8);

        __syncthreads();

        const unsigned short* yb = yp + ((size_t)b * M + ms * 512) * C;

        bf16x8 bfr = *(const bf16x8*)(yb + (size_t)col * C + quad * 8);
        for (int mt = 0; mt < 32; ++mt) {
            bf16x8 bnx = bfr;
            if (mt < 31)
                bnx = *(const bf16x8*)(yb + (size_t)((mt + 1) * 16 + col) * C + quad * 8);
            const float y2c  = y2s[mt * 16 + col];
            const int   mcur = ms * 512 + mt * 16 + col;   // col == this lane's m column
            #pragma unroll
            for (int t = 0; t < 4; ++t) {
                f32x4 acc = {y2c, y2c, y2c, y2c};
                acc = __builtin_amdgcn_mfma_f32_16x16x32_bf16(af[t], bfr, acc, 0, 0, 0);
                #pragma unroll
                for (int r = 0; r < 4; ++r) {
                    if (acc[r] > bD[t][r]) { bD[t][r] = acc[r]; bI[t][r] = mcur; }
                }
            }
            bfr = bnx;
        }
    } else {
        // ============ f32 path: exact split-bf16 MFMA (9 terms) ============
        const float* yp = (const float*)yptr;
        const float* xp = (const float*)xptr;

        // ---- stage -0.5*y2 (f32, linear fma chain) ----
        for (int r = tid; r < 512; r += 256) {
            const float* p = yp + ((size_t)b * M + ms * 512 + r) * C;
            float s = 0.f;
            #pragma unroll
            for (int i = 0; i < 8; ++i) {
                float4 v = *(const float4*)(p + i * 4);
                s = fmaf(v.x, v.x, s); s = fmaf(v.y, v.y, s);
                s = fmaf(v.z, v.z, s); s = fmaf(v.w, v.w, s);
            }
            y2s[r] = -0.5f * s;
        }

        // ---- A fragments: 3 planes per tile ----
        bf16x8 ah[4], am[4], al[4];
        #pragma unroll
        for (int t = 0; t < 4; ++t) {
            const float* xr = xp + ((size_t)b * N + n_base + t * 16 + col) * C + quad * 8;
            float4 v0 = *(const float4*)xr;
            float4 v1 = *(const float4*)(xr + 4);
            const float xf[8] = {v0.x, v0.y, v0.z, v0.w, v1.x, v1.y, v1.z, v1.w};
            split3(xf, ah[t], am[t], al[t]);
        }

        __syncthreads();

        const float* yb = yp + ((size_t)b * M + ms * 512) * C;

        const float* y0 = yb + (size_t)col * C + quad * 8;
        float4 c0 = *(const float4*)y0;
        float4 c1 = *(const float4*)(y0 + 4);

        for (int mt = 0; mt < 32; ++mt) {
            float4 n0 = c0, n1 = c1;
            if (mt < 31) {
                const float* nr = yb + (size_t)((mt + 1) * 16 + col) * C + quad * 8;
                n0 = *(const float4*)nr;
                n1 = *(const float4*)(nr + 4);
            }
            const float cf[8] = {c0.x, c0.y, c0.z, c0.w, c1.x, c1.y, c1.z, c1.w};
            bf16x8 bh, bm, bl;
            split3(cf, bh, bm, bl);

            const float y2c  = y2s[mt * 16 + col];
            const int   mcur = ms * 512 + mt * 16 + col;
            #pragma unroll
            for (int t = 0; t < 4; ++t) {
                f32x4 acc = {y2c, y2c, y2c, y2c};
                // all 9 cross-products of (ah+am+al)*(bh+bm+bl); every product
                // is exact in bf16 MFMA, so sum == f32 dot up to accumulation
                // rounding only.
                acc = __builtin_amdgcn_mfma_f32_16x16x32_bf16(ah[t], bh, acc, 0, 0, 0);
                acc = __builtin_amdgcn_mfma_f32_16x16x32_bf16(am[t], bh, acc, 0, 0, 0);
                acc = __builtin_amdgcn_mfma_f32_16x16x32_bf16(al[t], bh, acc, 0, 0, 0);
                acc = __builtin_amdgcn_mfma_f32_16x16x32_bf16(ah[t], bm, acc, 0, 0, 0);
                acc = __builtin_amdgcn_mfma_f32_16x16x32_bf16(am[t], bm, acc, 0, 0, 0);
                acc = __builtin_amdgcn_mfma_f32_16x16x32_bf16(al[t], bm, acc, 0, 0, 0);
                acc = __builtin_amdgcn_mfma_f32_16x16x32_bf16(ah[t], bl, acc, 0, 0, 0);
                acc = __builtin_amdgcn_mfma_f32_16x16x32_bf16(am[t], bl, acc, 0, 0, 0);
                acc = __builtin_amdgcn_mfma_f32_16x16x32_bf16(al[t], bl, acc, 0, 0, 0);
                #pragma unroll
                for (int r = 0; r < 4; ++r) {
                    if (acc[r] > bD[t][r]) { bD[t][r] = acc[r]; bI[t][r] = mcur; }
                }
            }
            c0 = n0; c1 = n1;
        }
    }

    // ---- butterfly over the 16 col-classes (lanes quad*16 + 0..15) ----
    #pragma unroll
    for (int mask = 1; mask < 16; mask <<= 1) {
        #pragma unroll
        for (int t = 0; t < 4; ++t)
            #pragma unroll
            for (int r = 0; r < 4; ++r) {
                float oD = __shfl_xor(bD[t][r], mask, 64);
                int   oI = __shfl_xor(bI[t][r], mask, 64);
                if (oD > bD[t][r] || (oD == bD[t][r] && oI < bI[t][r])) {
                    bD[t][r] = oD; bI[t][r] = oI;
                }
            }
    }

    // tracker (t,r) of lane-group quad holds row n_base + t*16 + quad*4 + r
    if (col == 0) {
        #pragma unroll
        for (int t = 0; t < 4; ++t)
            #pragma unroll
            for (int r = 0; r < 4; ++r) {
                const int n = n_base + t * 16 + quad * 4 + r;
                const size_t g = (size_t)ms * BN + (size_t)b * N + n;
                wD[g] = bD[t][r];
                wI[g] = bI[t][r];
            }
    }
}

// Combine the 8 m-split candidate slots and gather y_c.
__global__ __launch_bounds__(256)
void nn_combine(const float* __restrict__ wD, const int* __restrict__ wI,
                const void* __restrict__ ycptr,
                const unsigned short* __restrict__ tptr,
                void* __restrict__ outptr) {
    const bool is_bf16 = (tptr[0] == 0x4120);
    const int i = blockIdx.x * 256 + threadIdx.x;
    if (i >= BN) return;
    const int b = i >> 12;  // N = 4096

    float bk = wD[i];
    int   bx = wI[i];
    #pragma unroll
    for (int s = 1; s < 8; ++s) {
        const float k  = wD[(size_t)s * BN + i];
        const int   ix = wI[(size_t)s * BN + i];
        if (k > bk || (k == bk && ix < bx)) { bk = k; bx = ix; }
    }

    const size_t src = ((size_t)b * M + bx) * 3;
    if (is_bf16) {
        const unsigned short* yc = (const unsigned short*)ycptr;
        unsigned short* o = (unsigned short*)outptr;
        o[i*3+0] = yc[src+0];
        o[i*3+1] = yc[src+1];
        o[i*3+2] = yc[src+2];
    } else {
        const float* yc = (const float*)ycptr;
        float* o = (float*)outptr;
        o[i*3+0] = yc[src+0];
        o[i*3+1] = yc[src+1];
        o[i*3+2] = yc[src+2];
    }
}

extern "C" void kernel_launch(void* const* d_in, const int* in_sizes, int n_in,
                              void* d_out, int out_size, void* d_ws, size_t ws_size,
                              hipStream_t stream) {
    const void* x  = d_in[0];
    const void* y  = d_in[1];
    const void* yc = d_in[2];
    const unsigned short* t = (const unsigned short*)d_in[3];

    float* wD = (float*)d_ws;                                    // 8 * BN floats
    int*   wI = (int*)((char*)d_ws + (size_t)8 * BN * sizeof(float));

    nn_main<<<512, 256, 0, stream>>>(x, y, t, wD, wI);
    nn_combine<<<(BN + 255) / 256, 256, 0, stream>>>(wD, wI, yc, t, d_out);
}

// Round 2
// 96.216 us; speedup vs baseline: 1.8409x; 1.0813x over previous
//
#include <hip/hip_runtime.h>

#define B 4
#define N 4096
#define M 4096
#define C 32
#define BN (B * N)

typedef short bf16x8 __attribute__((ext_vector_type(8)));  // 8 bf16 in 4 VGPRs
typedef float f32x4  __attribute__((ext_vector_type(4)));
typedef unsigned int u32x4 __attribute__((ext_vector_type(4)));

// Workspace layout (bytes). Total ~4.2 MB.
#define WS_WI ((size_t)8 * BN * 4)                       // wD @ 0, wI @ WS_WI
#define WS_YH (WS_WI * 2)                                // bf16 hi plane of y
#define WS_YM (WS_YH + (size_t)B * M * C * 2)            // mid plane
#define WS_YL (WS_YM + (size_t)B * M * C * 2)            // lo plane
#define WS_Y2 (WS_YL + (size_t)B * M * C * 2)            // -0.5*y2 (f32)

__device__ __forceinline__ float bf16lo(unsigned int u) { return __uint_as_float(u << 16); }
__device__ __forceinline__ float bf16hi(unsigned int u) { return __uint_as_float(u & 0xffff0000u); }

// Exact 3-way truncation split of 8 f32 values into 3 bf16x8 planes.
// f32 mantissa = 24 bits; each plane captures >=8 bits and each residual
// subtraction is exact, so f = h + m + l EXACTLY.
__device__ __forceinline__ void split3(const float f[8], bf16x8& h, bf16x8& m, bf16x8& l) {
    u32x4 hw, mw, lw;
    #pragma unroll
    for (int p = 0; p < 4; ++p) {
        const float f0 = f[2*p], f1 = f[2*p+1];
        const unsigned int h0 = __float_as_uint(f0) & 0xffff0000u;
        const unsigned int h1 = __float_as_uint(f1) & 0xffff0000u;
        hw[p] = h1 | (h0 >> 16);
        const float r0 = f0 - __uint_as_float(h0);
        const float r1 = f1 - __uint_as_float(h1);
        const unsigned int m0 = __float_as_uint(r0) & 0xffff0000u;
        const unsigned int m1 = __float_as_uint(r1) & 0xffff0000u;
        mw[p] = m1 | (m0 >> 16);
        const float s0 = r0 - __uint_as_float(m0);
        const float s1 = r1 - __uint_as_float(m1);
        lw[p] = (__float_as_uint(s1) & 0xffff0000u) | (__float_as_uint(s0) >> 16);
    }
    h = __builtin_bit_cast(bf16x8, hw);
    m = __builtin_bit_cast(bf16x8, mw);
    l = __builtin_bit_cast(bf16x8, lw);
}

// Pre-pass (f32 mode only): split y into 3 bf16 planes + compute -0.5*y2.
// Removes all per-mt conversion VALU from nn_main's critical path (the same
// y-chunk was being re-split 64x: 4 waves/block x 16 blocks sharing it).
// Grid: 256 blocks x 256 threads = 65536 = B*M*4; each thread handles 8 elems.
__global__ __launch_bounds__(256)
void y_prepass(const void* __restrict__ yptr, const unsigned short* __restrict__ tptr,
               void* __restrict__ ws) {
    if (tptr[0] == 0x4120) return;   // bf16 inputs: planes unused
    unsigned short* yh = (unsigned short*)((char*)ws + WS_YH);
    unsigned short* ym = (unsigned short*)((char*)ws + WS_YM);
    unsigned short* yl = (unsigned short*)((char*)ws + WS_YL);
    float*          y2 = (float*)((char*)ws + WS_Y2);

    const int gid = blockIdx.x * 256 + threadIdx.x;
    const int row = gid >> 2;
    const int seg = gid & 3;
    const float* p = (const float*)yptr + (size_t)row * C + seg * 8;
    float4 v0 = *(const float4*)p;
    float4 v1 = *(const float4*)(p + 4);
    const float f[8] = {v0.x, v0.y, v0.z, v0.w, v1.x, v1.y, v1.z, v1.w};

    bf16x8 h, m, l;
    split3(f, h, m, l);
    const size_t o = (size_t)row * C + seg * 8;
    *(bf16x8*)(yh + o) = h;
    *(bf16x8*)(ym + o) = m;
    *(bf16x8*)(yl + o) = l;

    float s = 0.f;
    #pragma unroll
    for (int k = 0; k < 8; ++k) s = fmaf(f[k], f[k], s);
    s += __shfl_xor(s, 1, 64);     // 4 consecutive lanes share a row
    s += __shfl_xor(s, 2, 64);
    if (seg == 0) y2[row] = -0.5f * s;
}

// Grid: 1024 blocks x 256 threads (4 blocks/CU, 16 waves/CU).
// bi -> ms = bi&7 (m-split of 512), nb = (bi>>3)&31 (128 n rows), b = bi>>8.
// Each wave: 32 n rows (2 MFMA n-tiles), scans 512 m via 32 m-tiles.
// Key = dot - y2/2 (argmax == argmin dist; x2 cancels). C-operand seeds -y2/2.
// f32 path: A split in-regs (once); B planes streamed pre-split -> inner loop
// is pure {3 loads, 18 MFMA, track}.
__global__ __launch_bounds__(256, 4)
void nn_main(const void* __restrict__ xptr, const void* __restrict__ yptr,
             const unsigned short* __restrict__ tptr, void* __restrict__ ws) {
    float* wD = (float*)ws;
    int*   wI = (int*)((char*)ws + WS_WI);
    const bool is_bf16 = (tptr[0] == 0x4120);  // bf16(10.0)=0x4120; f32 low half = 0x0000

    __shared__ float y2s[512];          // -0.5*y2 for this m-split

    const int tid  = threadIdx.x;
    const int lane = tid & 63;
    const int wv   = tid >> 6;
    const int col  = lane & 15;
    const int quad = lane >> 4;
    const int bi   = blockIdx.x;
    const int ms   = bi & 7;
    const int nb   = (bi >> 3) & 31;
    const int b    = bi >> 8;
    const int n_base = nb * 128 + wv * 32;

    float bD[2][4];
    int   bI[2][4];
    #pragma unroll
    for (int t = 0; t < 2; ++t)
        #pragma unroll
        for (int r = 0; r < 4; ++r) { bD[t][r] = -__builtin_inff(); bI[t][r] = 0; }

    const size_t boff = (size_t)col * C + quad * 8;

    if (is_bf16) {
        const unsigned short* yp = (const unsigned short*)yptr;
        const unsigned short* xp = (const unsigned short*)xptr;

        // ---- stage -0.5*y2 for the 512 m rows of this split ----
        for (int r = tid; r < 512; r += 256) {
            const int m = ms * 512 + r;
            const uint4* p = (const uint4*)(yp + ((size_t)b * M + m) * C);
            float s = 0.f;
            #pragma unroll
            for (int i = 0; i < 4; ++i) {
                uint4 v = p[i];
                float f;
                f = bf16lo(v.x); s = fmaf(f, f, s); f = bf16hi(v.x); s = fmaf(f, f, s);
                f = bf16lo(v.y); s = fmaf(f, f, s); f = bf16hi(v.y); s = fmaf(f, f, s);
                f = bf16lo(v.z); s = fmaf(f, f, s); f = bf16hi(v.z); s = fmaf(f, f, s);
                f = bf16lo(v.w); s = fmaf(f, f, s); f = bf16hi(v.w); s = fmaf(f, f, s);
            }
            y2s[r] = -0.5f * s;
        }

        bf16x8 af[2];
        #pragma unroll
        for (int t = 0; t < 2; ++t)
            af[t] = *(const bf16x8*)(xp + ((size_t)b * N + n_base + t * 16 + col) * C + quad * 8);

        __syncthreads();

        const unsigned short* yb = yp + ((size_t)b * M + ms * 512) * C;
        bf16x8 bfr = *(const bf16x8*)(yb + boff);
        for (int mt = 0; mt < 32; ++mt) {
            bf16x8 bnx = bfr;
            if (mt < 31) bnx = *(const bf16x8*)(yb + boff + (size_t)(mt + 1) * (16 * C));
            const float y2c  = y2s[mt * 16 + col];
            const int   mcur = ms * 512 + mt * 16 + col;
            #pragma unroll
            for (int t = 0; t < 2; ++t) {
                f32x4 acc = {y2c, y2c, y2c, y2c};
                acc = __builtin_amdgcn_mfma_f32_16x16x32_bf16(af[t], bfr, acc, 0, 0, 0);
                #pragma unroll
                for (int r = 0; r < 4; ++r)
                    if (acc[r] > bD[t][r]) { bD[t][r] = acc[r]; bI[t][r] = mcur; }
            }
            bfr = bnx;
        }
    } else {
        // ============ f32 path: pre-split planes, 9 exact MFMA terms ============
        const unsigned short* yh = (const unsigned short*)((char*)ws + WS_YH) + ((size_t)b * M + ms * 512) * C;
        const unsigned short* ym = (const unsigned short*)((char*)ws + WS_YM) + ((size_t)b * M + ms * 512) * C;
        const unsigned short* yl = (const unsigned short*)((char*)ws + WS_YL) + ((size_t)b * M + ms * 512) * C;
        const float*         y2g = (const float*)((char*)ws + WS_Y2) + (size_t)b * M + ms * 512;

        for (int r = tid; r < 512; r += 256) y2s[r] = y2g[r];

        // A fragments: 3 planes per tile, split once in registers
        const float* xp = (const float*)xptr;
        bf16x8 ah[2], am[2], al[2];
        #pragma unroll
        for (int t = 0; t < 2; ++t) {
            const float* xr = xp + ((size_t)b * N + n_base + t * 16 + col) * C + quad * 8;
            float4 v0 = *(const float4*)xr;
            float4 v1 = *(const float4*)(xr + 4);
            const float xf[8] = {v0.x, v0.y, v0.z, v0.w, v1.x, v1.y, v1.z, v1.w};
            split3(xf, ah[t], am[t], al[t]);
        }

        __syncthreads();

        bf16x8 bh = *(const bf16x8*)(yh + boff);
        bf16x8 bmi = *(const bf16x8*)(ym + boff);
        bf16x8 bl = *(const bf16x8*)(yl + boff);
        for (int mt = 0; mt < 32; ++mt) {
            bf16x8 nh = bh, nm = bmi, nl = bl;
            if (mt < 31) {
                const size_t no = boff + (size_t)(mt + 1) * (16 * C);
                nh = *(const bf16x8*)(yh + no);
                nm = *(const bf16x8*)(ym + no);
                nl = *(const bf16x8*)(yl + no);
            }
            const float y2c  = y2s[mt * 16 + col];
            const int   mcur = ms * 512 + mt * 16 + col;
            #pragma unroll
            for (int t = 0; t < 2; ++t) {
                f32x4 acc = {y2c, y2c, y2c, y2c};
                // all 9 cross-products; same term order as the verified kernel
                acc = __builtin_amdgcn_mfma_f32_16x16x32_bf16(ah[t], bh,  acc, 0, 0, 0);
                acc = __builtin_amdgcn_mfma_f32_16x16x32_bf16(am[t], bh,  acc, 0, 0, 0);
                acc = __builtin_amdgcn_mfma_f32_16x16x32_bf16(al[t], bh,  acc, 0, 0, 0);
                acc = __builtin_amdgcn_mfma_f32_16x16x32_bf16(ah[t], bmi, acc, 0, 0, 0);
                acc = __builtin_amdgcn_mfma_f32_16x16x32_bf16(am[t], bmi, acc, 0, 0, 0);
                acc = __builtin_amdgcn_mfma_f32_16x16x32_bf16(al[t], bmi, acc, 0, 0, 0);
                acc = __builtin_amdgcn_mfma_f32_16x16x32_bf16(ah[t], bl,  acc, 0, 0, 0);
                acc = __builtin_amdgcn_mfma_f32_16x16x32_bf16(am[t], bl,  acc, 0, 0, 0);
                acc = __builtin_amdgcn_mfma_f32_16x16x32_bf16(al[t], bl,  acc, 0, 0, 0);
                #pragma unroll
                for (int r = 0; r < 4; ++r)
                    if (acc[r] > bD[t][r]) { bD[t][r] = acc[r]; bI[t][r] = mcur; }
            }
            bh = nh; bmi = nm; bl = nl;
        }
    }

    // ---- butterfly over the 16 col-classes (lanes quad*16 + 0..15) ----
    #pragma unroll
    for (int mask = 1; mask < 16; mask <<= 1) {
        #pragma unroll
        for (int t = 0; t < 2; ++t)
            #pragma unroll
            for (int r = 0; r < 4; ++r) {
                float oD = __shfl_xor(bD[t][r], mask, 64);
                int   oI = __shfl_xor(bI[t][r], mask, 64);
                if (oD > bD[t][r] || (oD == bD[t][r] && oI < bI[t][r])) {
                    bD[t][r] = oD; bI[t][r] = oI;
                }
            }
    }

    // tracker (t,r) of lane-group quad holds row n_base + t*16 + quad*4 + r
    if (col == 0) {
        #pragma unroll
        for (int t = 0; t < 2; ++t)
            #pragma unroll
            for (int r = 0; r < 4; ++r) {
                const int n = n_base + t * 16 + quad * 4 + r;
                const size_t g = (size_t)ms * BN + (size_t)b * N + n;
                wD[g] = bD[t][r];
                wI[g] = bI[t][r];
            }
    }
}

// Combine the 8 m-split slots and gather y_c.
// Parallelized: 8 lanes per row (s = lane>>3), coalesced slot reads,
// 3-step shfl_xor reduce, lane s==0 gathers. Grid: 512 blocks (32 rows/block).
__global__ __launch_bounds__(256)
void nn_combine(const float* __restrict__ wD, const int* __restrict__ wI,
                const void* __restrict__ ycptr,
                const unsigned short* __restrict__ tptr,
                void* __restrict__ outptr) {
    const bool is_bf16 = (tptr[0] == 0x4120);
    const int tid  = threadIdx.x;
    const int lane = tid & 63;
    const int wv   = tid >> 6;
    const int s    = lane >> 3;
    const int ro   = lane & 7;
    const int row  = blockIdx.x * 32 + wv * 8 + ro;

    float k  = wD[(size_t)s * BN + row];
    int   ix = wI[(size_t)s * BN + row];
    #pragma unroll
    for (int mask = 8; mask < 64; mask <<= 1) {
        float ok = __shfl_xor(k, mask, 64);
        int   oi = __shfl_xor(ix, mask, 64);
        if (ok > k || (ok == k && oi < ix)) { k = ok; ix = oi; }
    }

    if (s == 0) {
        const int b = row >> 12;  // N = 4096
        const size_t src = ((size_t)b * M + ix) * 3;
        if (is_bf16) {
            const unsigned short* yc = (const unsigned short*)ycptr;
            unsigned short* o = (unsigned short*)outptr;
            o[row*3+0] = yc[src+0];
            o[row*3+1] = yc[src+1];
            o[row*3+2] = yc[src+2];
        } else {
            const float* yc = (const float*)ycptr;
            float* o = (float*)outptr;
            o[row*3+0] = yc[src+0];
            o[row*3+1] = yc[src+1];
            o[row*3+2] = yc[src+2];
        }
    }
}

extern "C" void kernel_launch(void* const* d_in, const int* in_sizes, int n_in,
                              void* d_out, int out_size, void* d_ws, size_t ws_size,
                              hipStream_t stream) {
    const void* x  = d_in[0];
    const void* y  = d_in[1];
    const void* yc = d_in[2];
    const unsigned short* t = (const unsigned short*)d_in[3];

    float* wD = (float*)d_ws;
    int*   wI = (int*)((char*)d_ws + WS_WI);

    y_prepass<<<256, 256, 0, stream>>>(y, t, d_ws);
    nn_main<<<1024, 256, 0, stream>>>(x, y, t, d_ws);
    nn_combine<<<512, 256, 0, stream>>>(wD, wI, yc, t, d_out);
}